// Round 9
// baseline (437.070 us; speedup 1.0000x reference)
//
#include <hip/hip_runtime.h>
#include <hip/hip_bf16.h>

// r11: 345.2us best (k_attn 121.5, k_qkv ~133). r12 FAILED: 64-row k_qkv tile 133->192
//      (staging/barrier overhead per work up; occupancy was a red herring).
// r13: k_qkv is LDS-read-pipe-bound (16 b128/wave-step, ~1536 cyc/CU vs 480 MFMA).
//      Fix: A operand direct global->reg (swizzle cancels; 1-step reg prefetch),
//      W keeps glds+LDS dbuf. LDS reads/step halved. vmcnt rebuilt: 12 / 6.
//      Guard: WRITE_SIZE ~68MB (jump = spill = revert). All else = r11.

typedef unsigned short u16;
typedef unsigned int   u32;
typedef __attribute__((ext_vector_type(4)))  float floatx4;
typedef __attribute__((ext_vector_type(16))) float floatx16;
typedef __attribute__((ext_vector_type(8)))  short shortx8;
typedef __attribute__((ext_vector_type(2)))  unsigned int uintx2;

#define EMB   768
#define SEQ   2048
#define NHEAD 12
#define HDIM  64
#define RPM   4096   // rows per modal (B*N)
#define NROW  8192   // total rows (2 modals)
#define NUNIT 48     // modal*B*H units
#define KTS   4096   // attn LDS tile elems (64*64)
#define CS_SCALE 11.5415603271f   // 8 * log2(e)

__device__ __forceinline__ float bf2f(u16 h) {
  union { u32 u; float f; } v; v.u = ((u32)h) << 16; return v.f;
}
__device__ __forceinline__ u16 f2bf(float f) {            // RNE
  union { float f; u32 u; } v; v.f = f;
  u32 r = v.u + 0x7fffu + ((v.u >> 16) & 1u);
  return (u16)(r >> 16);
}
__device__ __forceinline__ u32 cvtpk_bf16(float a, float b) {  // lo16=bf16(a), hi16=bf16(b)
  u32 r;
  asm("v_cvt_pk_bf16_f32 %0, %1, %2" : "=v"(r) : "v"(a), "v"(b));
  return r;
}
// x = {a.lo32lanes, b.lo32lanes}, y = {a.hi32lanes, b.hi32lanes}
__device__ __forceinline__ void swap_halves(u32 a, u32 b, u32& x, u32& y) {
#if __has_builtin(__builtin_amdgcn_permlane32_swap)
  uintx2 r = __builtin_amdgcn_permlane32_swap(a, b, false, false);
  x = r.x; y = r.y;
#else
  u32 ax = (u32)__shfl_xor((int)a, 32);
  u32 bx = (u32)__shfl_xor((int)b, 32);
  bool h = (threadIdx.x & 32) != 0;
  x = h ? bx : a;
  y = h ? b : ax;
#endif
}

// ---------------- merged prep: wq split (bx<4608) + LayerNorm (bx>=4608) ----------------
__global__ __launch_bounds__(256) void k_pre(
    const float* __restrict__ wq1, const float* __restrict__ wq2,
    u16* __restrict__ wh, u16* __restrict__ wl,
    const float* __restrict__ x1, const float* __restrict__ x2,
    const float* __restrict__ g1, const float* __restrict__ b1,
    const float* __restrict__ g2, const float* __restrict__ b2,
    u16* __restrict__ xn_hi, u16* __restrict__ xn_lo)
{
  int bx = blockIdx.x;
  int t = threadIdx.x;
  if (bx < 4608) {
    // ---- prep_wq: split qkv weights fp32 -> bf16 hi/lo, permuted ----
    int modal = bx / 2304, rowp = bx % 2304;
    int typ = rowp / 768, hd = rowp % 768;
    const float* W = (modal ? wq2 : wq1) + (size_t)(hd * 3 + typ) * EMB;
    size_t dst = (size_t)bx * EMB;
    #pragma unroll
    for (int i = 0; i < 3; ++i) {
      int e = t + i * 256;
      float v = W[e];
      u16 h = f2bf(v);
      wh[dst + e] = h;
      wl[dst + e] = f2bf(v - bf2f(h));
    }
  } else {
    // ---- k_ln: LayerNorm (fp32 in) + hi/lo bf16 split ----
    int row = bx - 4608;                // 0..8191, modal-major
    int modal = row >> 12;
    const float* x = modal ? x2 : x1;
    const float* g = modal ? g2 : g1;
    const float* bb = modal ? b2 : b1;
    int r = row & (RPM - 1);
    const float* xr = x + (size_t)r * EMB;
    float v0 = xr[t], v1 = xr[t + 256], v2 = xr[t + 512];
    float s = v0 + v1 + v2;
    float s2 = v0 * v0 + v1 * v1 + v2 * v2;
    #pragma unroll
    for (int m = 1; m < 64; m <<= 1) { s += __shfl_xor(s, m); s2 += __shfl_xor(s2, m); }
    __shared__ float ls[4], ls2[4];
    int w = t >> 6;
    if ((t & 63) == 0) { ls[w] = s; ls2[w] = s2; }
    __syncthreads();
    s = ls[0] + ls[1] + ls[2] + ls[3];
    s2 = ls2[0] + ls2[1] + ls2[2] + ls2[3];
    float mu = s * (1.0f / EMB);
    float var = s2 * (1.0f / EMB) - mu * mu;
    float rs = rsqrtf(var + 1e-5f);
    size_t base = (size_t)row * EMB;
    float vv[3] = { v0, v1, v2 };
    #pragma unroll
    for (int i = 0; i < 3; ++i) {
      int e = t + i * 256;
      float xn = (vv[i] - mu) * rs * g[e] + bb[e];
      u16 h = f2bf(xn);
      xn_hi[base + e] = h;
      xn_lo[base + e] = f2bf(xn - bf2f(h));
    }
  }
}

// prep: w_proj fp32 -> bf16 hi only (runs after k_attn; wp_h aliases dead q_lo)
__global__ __launch_bounds__(256) void prep_wp(
    const float* __restrict__ wp1, const float* __restrict__ wp2,
    u16* __restrict__ wh)
{
  int bx = blockIdx.x;                  // 0..1535
  int modal = bx / 768, row = bx % 768;
  const float* W = (modal ? wp2 : wp1) + (size_t)row * EMB;
  size_t dst = (size_t)bx * EMB;
  int t = threadIdx.x;
  #pragma unroll
  for (int i = 0; i < 3; ++i) {
    int e = t + i * 256;
    wh[dst + e] = f2bf(W[e]);
  }
}

// ---------------- Kernel 2: QKV GEMM, tile 128x128, A-direct-to-reg, W via LDS dbuf ----
// grid (32,18,2), 256 thr, BK=32. A (xn hi/lo) loaded global->reg with 1-step prefetch
// (swizzle cancels: addr = row*EMB + k0 + lq*8). W staged via global_load_lds, 2-phase
// counted-vmcnt dbuf (LDS 32KB total). Q output pre-scaled by CS_SCALE.
__global__ __launch_bounds__(256) void k_qkv(
    const u16* __restrict__ xn_hi, const u16* __restrict__ xn_lo,
    const u16* __restrict__ wqh, const u16* __restrict__ wql,
    const float* __restrict__ bq1, const float* __restrict__ bq2,
    u16* __restrict__ q_hi, u16* __restrict__ q_lo,
    u16* __restrict__ k_hi, u16* __restrict__ k_lo,
    u16* __restrict__ vT)
{
  int mt = blockIdx.x, ntile = blockIdx.y, modal = blockIdx.z;
  const float* BQ = modal ? bq2 : bq1;
  int typ = ntile / 6;            // 0=q 1=k 2=v
  int hd0 = (ntile % 6) * 128;

  __shared__ __align__(16) u16 Wh[2][128 * 32], Wl[2][128 * 32];

  int tid = threadIdx.x, lane = tid & 63, w = tid >> 6;
  int wm = (w >> 1) * 64, wn = (w & 1) * 64;
  int lc = lane & 15, lq = lane >> 4;

  int srow = lane >> 2;                          // 0..15: row within 16-row segment
  int schunk = ((lane & 3) ^ (srow & 3)) << 3;   // pre-swizzled source chunk (u16 units)

  floatx4 acc[4][4] = {};
  const u16* aH = xn_hi + (size_t)(modal * RPM + mt * 128) * EMB;
  const u16* aL = xn_lo + (size_t)(modal * RPM + mt * 128) * EMB;
  const u16* wH = wqh + (size_t)(modal * 2304 + typ * 768 + hd0) * EMB;
  const u16* wL = wql + (size_t)(modal * 2304 + typ * 768 + hd0) * EMB;

  // W segments (1KB = 16 rows x 32 elems): typ!=2: segs 0-7 Wh, 8-15 Wl (4/wave);
  //                                        typ==2: segs 0-7 Wh (2/wave).
  auto stageW = [&](int buf, int k0) {
    if (typ != 2) {
      #pragma unroll
      for (int c = 0; c < 4; ++c) {
        int seg = w * 4 + c;                     // 0..15
        const u16* src; u16* dstb; int segin;
        if (seg < 8) { segin = seg;     src = wH; dstb = &Wh[buf][0]; }
        else         { segin = seg - 8; src = wL; dstb = &Wl[buf][0]; }
        size_t off = (size_t)(segin * 16 + srow) * EMB + k0 + schunk;
        __builtin_amdgcn_global_load_lds(
            (const __attribute__((address_space(1))) unsigned int*)(src + off),
            (__attribute__((address_space(3))) unsigned int*)(dstb + segin * 512), 16, 0, 0);
      }
    } else {
      #pragma unroll
      for (int c = 0; c < 2; ++c) {
        int seg = w * 2 + c;                     // 0..7
        size_t off = (size_t)(seg * 16 + srow) * EMB + k0 + schunk;
        __builtin_amdgcn_global_load_lds(
            (const __attribute__((address_space(1))) unsigned int*)(wH + off),
            (__attribute__((address_space(3))) unsigned int*)(&Wh[buf][0] + seg * 512), 16, 0, 0);
      }
    }
  };

  // A direct: frag i = rows wm+i*16+lc, k-elems k0 + lq*8 .. +8 (16B, 64B/row group)
  size_t abase = (size_t)(wm + lc) * EMB + lq * 8;
  shortx8 ahN[4], alN[4];
  auto loadA = [&](int k0) {
    #pragma unroll
    for (int i = 0; i < 4; ++i) {
      size_t o = abase + (size_t)(i * 16) * EMB + k0;
      ahN[i] = *(const shortx8*)(aH + o);
      if (typ != 2) alN[i] = *(const shortx8*)(aL + o);
    }
  };

  loadA(0);
  stageW(0, 0);
  for (int kk = 0; kk < 24; ++kk) {
    int cur = kk & 1;
    bool more = (kk + 1 < 24);
    // consume prefetched A (compiler inserts the vmcnt wait for these regs; the loads
    // were issued a full iteration ago so the wait is ~free)
    shortx8 ah[4], al[4];
    #pragma unroll
    for (int i = 0; i < 4; ++i) { ah[i] = ahN[i]; if (typ != 2) al[i] = alN[i]; }
    if (more) { loadA((kk + 1) * 32); stageW(cur ^ 1, (kk + 1) * 32); }
    // wait W(cur) landed; leave A(next)+W(next) in flight: 8+4=12 (typ2: 4+2=6)
    if (typ != 2) {
      if (more) asm volatile("s_waitcnt vmcnt(12)" ::: "memory");
      else      asm volatile("s_waitcnt vmcnt(0)" ::: "memory");
    } else {
      if (more) asm volatile("s_waitcnt vmcnt(6)" ::: "memory");
      else      asm volatile("s_waitcnt vmcnt(0)" ::: "memory");
    }
    __builtin_amdgcn_s_barrier();
    __builtin_amdgcn_sched_barrier(0);

    int ca = (lq ^ (lc & 3)) << 3;               // swizzled read chunk (u16 units)
    shortx8 whf[4], wlf[4];
    #pragma unroll
    for (int i = 0; i < 4; ++i) {
      int rw = wn + i * 16 + lc;
      whf[i] = *(const shortx8*)&Wh[cur][rw * 32 + ca];
      if (typ != 2) wlf[i] = *(const shortx8*)&Wl[cur][rw * 32 + ca];
    }
    #pragma unroll
    for (int i = 0; i < 4; ++i)
      #pragma unroll
      for (int jn = 0; jn < 4; ++jn) {
        acc[i][jn] = __builtin_amdgcn_mfma_f32_16x16x32_bf16(ah[i], whf[jn], acc[i][jn], 0, 0, 0);
        if (typ != 2) {
          acc[i][jn] = __builtin_amdgcn_mfma_f32_16x16x32_bf16(al[i], whf[jn], acc[i][jn], 0, 0, 0);
          acc[i][jn] = __builtin_amdgcn_mfma_f32_16x16x32_bf16(ah[i], wlf[jn], acc[i][jn], 0, 0, 0);
        }
      }
    // this wave's LDS reads fully drained before signaling tile-done
    asm volatile("s_waitcnt lgkmcnt(0)" ::: "memory");
    __builtin_amdgcn_s_barrier();
    __builtin_amdgcn_sched_barrier(0);
  }

  #pragma unroll
  for (int i = 0; i < 4; ++i) {
    int mrow0 = mt * 128 + wm + i * 16 + lq * 4;
    #pragma unroll
    for (int jn = 0; jn < 4; ++jn) {
      int colp = hd0 + wn + jn * 16 + lc;          // hd index [0,768)
      int h = colp >> 6, d = colp & 63;
      float bias = BQ[colp * 3 + typ];
      #pragma unroll
      for (int r = 0; r < 4; ++r) {
        int mrow = mrow0 + r;
        int b = mrow >> 11, nq = mrow & (SEQ - 1);
        int uu = modal * 24 + b * 12 + h;
        float val = acc[i][jn][r] + bias;
        if (typ == 0) {
          val *= CS_SCALE;                       // pre-scale Q into log2-softmax domain
          size_t o = ((size_t)uu * SEQ + nq) * HDIM + d;
          u16 hh = f2bf(val); q_hi[o] = hh; q_lo[o] = f2bf(val - bf2f(hh));
        } else if (typ == 1) {
          size_t o = ((size_t)uu * SEQ + nq) * HDIM + d;
          u16 hh = f2bf(val); k_hi[o] = hh; k_lo[o] = f2bf(val - bf2f(hh));
        } else {
          vT[((size_t)uu * HDIM + d) * SEQ + nq] = f2bf(val);
        }
      }
    }
  }
}

// ---------------- Kernel 3: flash attention (r11 body, verified 121.5us) ----------
// grid (16,48) XCD-remapped (K/V L2-resident, FETCH 32MB). Q pre-scaled -> S in log2
// domain. Per-slice fused {exp2 -> lsum -> pack -> PV}.
__global__ __launch_bounds__(256, 3) void k_attn(
    const u16* __restrict__ q_hi, const u16* __restrict__ q_lo,
    const u16* __restrict__ k_hi, const u16* __restrict__ k_lo,
    const u16* __restrict__ vT, u16* __restrict__ attn_out)
{
  int id = blockIdx.x + (blockIdx.y << 4);       // 0..767
  int xcd = id & 7, j = id >> 3;                 // j: 0..95
  int u = xcd * 6 + (j >> 4);                    // 6 units per XCD
  int qt = j & 15;

  // [buf][tile]: tile 0 = K_hi [64k][64d], 1 = K_lo, 2 = V^T [64d][64k]; XOR-swizzled
  __shared__ __align__(16) u16 lds[2][3 * KTS];

  int tid = threadIdx.x, lane = tid & 63, w = tid >> 6;
  int col = lane & 31, hi = lane >> 5;
  int swz = (col & 7) << 4;              // read-side swizzle: row&7 == col&7 for all our reads

  // ---- Q fragments in regs: lane holds q = base+col, d = s*16 + hi*8 + 0..7 ----
  shortx8 qh[4], qlo[4];
  {
    size_t qb = ((size_t)u * SEQ + qt * 128 + w * 32 + col) * HDIM + hi * 8;
    #pragma unroll
    for (int s = 0; s < 4; ++s) {
      qh[s]  = *(const shortx8*)(q_hi + qb + s * 16);
      qlo[s] = *(const shortx8*)(q_lo + qb + s * 16);
    }
  }

  // ---- staging: 24 x 1KB segments via global_load_lds; source pre-swizzled ----
  int lrow = lane >> 3;                          // 0..7 (row within 8-row segment)
  int lcol = ((lane & 7) ^ lrow) << 3;           // swizzled elem offset within 64
  const u16* kh_src = k_hi + (size_t)u * SEQ * HDIM;
  const u16* kl_src = k_lo + (size_t)u * SEQ * HDIM;
  const u16* v_src  = vT  + (size_t)u * HDIM * SEQ;

  auto stage = [&](int buf, int kc) {
    #pragma unroll
    for (int c = 0; c < 6; ++c) {
      int seg = w * 6 + c;                       // 0..23, wave-uniform
      int tile = seg >> 3, segin = seg & 7;
      u16* dst = &lds[buf][tile * KTS + segin * 512];
      const u16* src;
      if (tile == 0)      src = kh_src + (size_t)(kc + segin * 8 + lrow) * HDIM + lcol;
      else if (tile == 1) src = kl_src + (size_t)(kc + segin * 8 + lrow) * HDIM + lcol;
      else                src = v_src  + (size_t)(segin * 8 + lrow) * SEQ + kc + lcol;
      __builtin_amdgcn_global_load_lds(
          (const __attribute__((address_space(1))) unsigned int*)src,
          (__attribute__((address_space(3))) unsigned int*)dst, 16, 0, 0);
    }
  };

  floatx16 O0 = {}, O1 = {};                     // O^T: lane col = d(+32*dt), regs = q (crow)
  float m_r = -1e30f, lsum = 0.0f;               // per-lane: q = col (log2 domain)
  const float THR = 8.0f;                        // defer-max threshold (log2 domain)

  stage(0, 0);
  __syncthreads();

  for (int t = 0; t < SEQ / 64; ++t) {
    int cur = t & 1;
    if (t + 1 < SEQ / 64) stage(cur ^ 1, (t + 1) * 64);

    const char* Kh = (const char*)&lds[cur][0];
    const char* Kl = (const char*)&lds[cur][KTS];
    const char* Vt = (const char*)&lds[cur][2 * KTS];

    // ---- swapped QK^T: S^T[k][q] in log2 domain (Q pre-scaled) ----
    floatx16 S0 = {}, S1 = {};
    __builtin_amdgcn_s_setprio(1);
    #pragma unroll
    for (int s = 0; s < 4; ++s) {
      int cb = (s * 32 + hi * 16) ^ swz;
      shortx8 kf0 = *(const shortx8*)(Kh + col * 128 + cb);
      shortx8 kl0 = *(const shortx8*)(Kl + col * 128 + cb);
      shortx8 kf1 = *(const shortx8*)(Kh + (32 + col) * 128 + cb);
      shortx8 kl1 = *(const shortx8*)(Kl + (32 + col) * 128 + cb);
      S0 = __builtin_amdgcn_mfma_f32_32x32x16_bf16(kf0, qh[s],  S0, 0, 0, 0);
      S1 = __builtin_amdgcn_mfma_f32_32x32x16_bf16(kf1, qh[s],  S1, 0, 0, 0);
      S0 = __builtin_amdgcn_mfma_f32_32x32x16_bf16(kf0, qlo[s], S0, 0, 0, 0);
      S1 = __builtin_amdgcn_mfma_f32_32x32x16_bf16(kf1, qlo[s], S1, 0, 0, 0);
      S0 = __builtin_amdgcn_mfma_f32_32x32x16_bf16(kl0, qh[s],  S0, 0, 0, 0);
      S1 = __builtin_amdgcn_mfma_f32_32x32x16_bf16(kl1, qh[s],  S1, 0, 0, 0);
    }
    __builtin_amdgcn_s_setprio(0);

    // ---- lane-local chunk max (tree, already log2-scaled), pair-reduce lane^32 ----
    float tm[16];
    #pragma unroll
    for (int r = 0; r < 16; ++r) tm[r] = fmaxf(S0[r], S1[r]);
    #pragma unroll
    for (int st = 8; st >= 1; st >>= 1)
      #pragma unroll
      for (int i = 0; i < st; ++i) tm[i] = fmaxf(tm[i], tm[i + st]);
    float mx = tm[0];
    mx = fmaxf(mx, __shfl_xor(mx, 32));

    // ---- defer-max rescale (T13): only when chunk max grows past m+THR ----
    if (!__all(mx <= m_r + THR)) {
      float mn = fmaxf(m_r, mx);
      float alpha = __builtin_amdgcn_exp2f(m_r - mn);
      m_r = mn;
      lsum *= alpha;
      #pragma unroll
      for (int r = 0; r < 16; ++r) {               // transpose alpha[q] into O lanes
        int qsrc = (r & 3) + 8 * (r >> 2) + 4 * hi;
        union { float f; int i; } a; a.f = alpha;
        a.i = __builtin_amdgcn_ds_bpermute(qsrc << 2, a.i);
        O0[r] *= a.f; O1[r] *= a.f;
      }
    }

    // ---- per-k-slice fused: exp2 -> lsum -> pack -> PV (MFMA/VALU interleave) ----
    __builtin_amdgcn_s_setprio(1);
    #pragma unroll
    for (int ks = 0; ks < 4; ++ks) {
      const int h2 = ks & 1;
      float ee[8];
      #pragma unroll
      for (int i = 0; i < 8; ++i) {
        float sv = (ks < 2) ? S0[h2 * 8 + i] : S1[h2 * 8 + i];
        ee[i] = __builtin_amdgcn_exp2f(sv - m_r);
      }
      lsum += ((ee[0] + ee[1]) + (ee[2] + ee[3])) + ((ee[4] + ee[5]) + (ee[6] + ee[7]));
      u32 A = cvtpk_bf16(ee[0], ee[1]);
      u32 B = cvtpk_bf16(ee[2], ee[3]);
      u32 C = cvtpk_bf16(ee[4], ee[5]);
      u32 D = cvtpk_bf16(ee[6], ee[7]);
      u32 w0, w1, w2, w3;
      swap_halves(A, C, w0, w2);
      swap_halves(B, D, w1, w3);
      union { u32 uu[4]; shortx8 ss; } pk_;
      pk_.uu[0] = w0; pk_.uu[1] = w1; pk_.uu[2] = w2; pk_.uu[3] = w3;
      int cb = (ks * 32 + hi * 16) ^ swz;
      shortx8 v0 = *(const shortx8*)(Vt + col * 128 + cb);
      shortx8 v1 = *(const shortx8*)(Vt + (32 + col) * 128 + cb);
      O0 = __builtin_amdgcn_mfma_f32_32x32x16_bf16(pk_.ss, v0, O0, 0, 0, 0);
      O1 = __builtin_amdgcn_mfma_f32_32x32x16_bf16(pk_.ss, v1, O1, 0, 0, 0);
    }
    __builtin_amdgcn_s_setprio(0);

    __syncthreads();   // drains vmcnt (next-buf DMA) + lgkm; all waves done reading cur
  }

  // ---- epilogue: l = pair-sum, transpose 1/l into O lanes, store ----
  float lt = lsum + __shfl_xor(lsum, 32);
  float rl = __builtin_amdgcn_rcpf(lt);
  int modal = u / 24, b = (u / 12) & 1, h = u % 12;
  size_t obase = ((size_t)(modal * RPM + b * SEQ + qt * 128 + w * 32)) * EMB + h * 64 + col;
  #pragma unroll
  for (int r = 0; r < 16; ++r) {
    int ql_ = (r & 3) + 8 * (r >> 2) + 4 * hi;     // q-local row of this reg
    union { float f; int i; } a; a.f = rl;
    a.i = __builtin_amdgcn_ds_bpermute(ql_ << 2, a.i);
    size_t ob = obase + (size_t)ql_ * EMB;
    attn_out[ob]      = f2bf(O0[r] * a.f);
    attn_out[ob + 32] = f2bf(O1[r] * a.f);
  }
}

// ---------------- Kernel 4: proj GEMM + bias + fp32 residual, 2-phase dbuf -------
// grid (64 row-tiles, 6 col-tiles, 2 modals), 256 thr. Tile 64x128, BK=32.
__global__ __launch_bounds__(256) void k_proj(
    const u16* __restrict__ ao, const u16* __restrict__ wph,
    const float* __restrict__ x1, const float* __restrict__ x2,
    const float* __restrict__ bp1, const float* __restrict__ bp2,
    float* __restrict__ out)
{
  int mt = blockIdx.x, ntile = blockIdx.y, modal = blockIdx.z;
  const float* BP = modal ? bp2 : bp1;
  const float* x  = modal ? x2 : x1;

  __shared__ __align__(16) u16 As[2][64 * 32], Ws[2][128 * 32];
  int tid = threadIdx.x, lane = tid & 63, w = tid >> 6;
  int wm = (w >> 1) * 32, wn = (w & 1) * 64;
  int lc = lane & 15, lq = lane >> 4;

  int srow = lane >> 2;                          // 0..15
  int schunk = ((lane & 3) ^ (srow & 3)) << 3;   // pre-swizzled source chunk

  floatx4 acc[2][4] = {};
  const u16* aP = ao  + (size_t)(modal * RPM + mt * 64) * EMB;
  const u16* wP = wph + (size_t)(modal * 768 + ntile * 128) * EMB;

  auto stage = [&](int buf, int k0) {
    #pragma unroll
    for (int c = 0; c < 3; ++c) {
      int seg = w * 3 + c;                       // 0..11: 0..3 = As, 4..11 = Ws
      const u16* src; u16* dst;
      if (seg < 4) {
        src = aP + (size_t)(seg * 16 + srow) * EMB + k0 + schunk;
        dst = &As[buf][0] + seg * 512;
      } else {
        int s2 = seg - 4;
        src = wP + (size_t)(s2 * 16 + srow) * EMB + k0 + schunk;
        dst = &Ws[buf][0] + s2 * 512;
      }
      __builtin_amdgcn_global_load_lds(
          (const __attribute__((address_space(1))) unsigned int*)src,
          (__attribute__((address_space(3))) unsigned int*)dst, 16, 0, 0);
    }
  };

  stage(0, 0);
  for (int kk = 0; kk < 24; ++kk) {
    int cur = kk & 1;
    bool more = (kk + 1 < 24);
    if (more) stage(cur ^ 1, (kk + 1) * 32);
    if (more) asm volatile("s_waitcnt vmcnt(3)" ::: "memory");
    else      asm volatile("s_waitcnt vmcnt(0)" ::: "memory");
    __builtin_amdgcn_s_barrier();
    __builtin_amdgcn_sched_barrier(0);

    int ca = (lq ^ (lc & 3)) << 3;
    shortx8 af[2], wf[4];
    #pragma unroll
    for (int i = 0; i < 2; ++i) af[i] = *(const shortx8*)&As[cur][(wm + i * 16 + lc) * 32 + ca];
    #pragma unroll
    for (int i = 0; i < 4; ++i) wf[i] = *(const shortx8*)&Ws[cur][(wn + i * 16 + lc) * 32 + ca];
    #pragma unroll
    for (int i = 0; i < 2; ++i)
      #pragma unroll
      for (int jn = 0; jn < 4; ++jn)
        acc[i][jn] = __builtin_amdgcn_mfma_f32_16x16x32_bf16(af[i], wf[jn], acc[i][jn], 0, 0, 0);
    asm volatile("s_waitcnt lgkmcnt(0)" ::: "memory");
    __builtin_amdgcn_s_barrier();
    __builtin_amdgcn_sched_barrier(0);
  }

  #pragma unroll
  for (int i = 0; i < 2; ++i) {
    int mrow0 = mt * 64 + wm + i * 16 + lq * 4;
    #pragma unroll
    for (int jn = 0; jn < 4; ++jn) {
      int col = ntile * 128 + wn + jn * 16 + lc;
      float bias = BP[col];
      #pragma unroll
      for (int r = 0; r < 4; ++r) {
        int mrow = mrow0 + r;
        float val = acc[i][jn][r] + bias + x[(size_t)mrow * EMB + col];
        out[((size_t)(modal * RPM + mrow)) * EMB + col] = val;
      }
    }
  }
}

extern "C" void kernel_launch(void* const* d_in, const int* in_sizes, int n_in,
                              void* d_out, int out_size, void* d_ws, size_t ws_size,
                              hipStream_t stream) {
  const float* modal1 = (const float*)d_in[0];
  const float* modal2 = (const float*)d_in[1];
  const float* ln1_g  = (const float*)d_in[2];
  const float* ln1_b  = (const float*)d_in[3];
  const float* w_qkv1 = (const float*)d_in[4];
  const float* b_qkv1 = (const float*)d_in[5];
  const float* w_proj1= (const float*)d_in[6];
  const float* b_proj1= (const float*)d_in[7];
  const float* ln2_g  = (const float*)d_in[8];
  const float* ln2_b  = (const float*)d_in[9];
  const float* w_qkv2 = (const float*)d_in[10];
  const float* b_qkv2 = (const float*)d_in[11];
  const float* w_proj2= (const float*)d_in[12];
  const float* b_proj2= (const float*)d_in[13];
  float* out = (float*)d_out;

  const size_t BUFE = (size_t)NROW * EMB;       // 6291456 elems
  const size_t WQE  = (size_t)2 * 2304 * EMB;   // 3538944 elems
  u16* xn_hi = (u16*)d_ws;
  u16* xn_lo = xn_hi + BUFE;
  u16* q_hi  = xn_lo + BUFE;
  u16* q_lo  = q_hi + BUFE;
  u16* k_hi  = q_lo + BUFE;
  u16* k_lo  = k_hi + BUFE;
  u16* vT    = k_lo + BUFE;
  u16* wq_h  = vT + BUFE;
  u16* wq_l  = wq_h + WQE;
  u16* attn  = xn_hi;   // xn dead after k_qkv
  u16* wp_h  = q_lo;    // q_lo dead after k_attn (w_proj needs 1.18M < 6.29M elems)

  k_pre<<<4608 + NROW, 256, 0, stream>>>(w_qkv1, w_qkv2, wq_h, wq_l,
                                         modal1, modal2, ln1_g, ln1_b, ln2_g, ln2_b,
                                         xn_hi, xn_lo);
  dim3 g2(32, 18, 2);
  k_qkv<<<g2, 256, 0, stream>>>(xn_hi, xn_lo, wq_h, wq_l, b_qkv1, b_qkv2,
                                q_hi, q_lo, k_hi, k_lo, vT);
  dim3 g3(16, 48);
  k_attn<<<g3, 256, 0, stream>>>(q_hi, q_lo, k_hi, k_lo, vT, attn);
  prep_wp<<<1536, 256, 0, stream>>>(w_proj1, w_proj2, wp_h);
  dim3 g4(64, 6, 2);
  k_proj<<<g4, 256, 0, stream>>>(attn, wp_h, modal1, modal2, b_proj1, b_proj2, out);
}

// Round 10
// 355.046 us; speedup vs baseline: 1.2310x; 1.2310x over previous
//
#include <hip/hip_runtime.h>
#include <hip/hip_bf16.h>

// r11: 345.2us best (k_attn 121.5, k_qkv <=127). r12 FAILED (64-row tile: overhead/work up).
// r13 FAILED (A-direct-to-reg: exposed L2 latency, MfmaUtil 21->13). Lesson: 2-phase GEMM's
// critical path is stage+vmcnt+barrier itself (guide T2/T3 regime gate); single-var fixes null.
// r14: k_qkv reverted to r11-exact + improved chunk swizzle f(r)=(r&3)^((r>>2)&3) (4-way ->
// 2-way read conflicts; store+read updated together). Same fix in k_proj. Diagnostic:
// conflict counter must drop <2.5M; if dur flat, structure confirmed phase-bound.

typedef unsigned short u16;
typedef unsigned int   u32;
typedef __attribute__((ext_vector_type(4)))  float floatx4;
typedef __attribute__((ext_vector_type(16))) float floatx16;
typedef __attribute__((ext_vector_type(8)))  short shortx8;
typedef __attribute__((ext_vector_type(2)))  unsigned int uintx2;

#define EMB   768
#define SEQ   2048
#define NHEAD 12
#define HDIM  64
#define RPM   4096   // rows per modal (B*N)
#define NROW  8192   // total rows (2 modals)
#define NUNIT 48     // modal*B*H units
#define KTS   4096   // attn LDS tile elems (64*64)
#define CS_SCALE 11.5415603271f   // 8 * log2(e)

__device__ __forceinline__ float bf2f(u16 h) {
  union { u32 u; float f; } v; v.u = ((u32)h) << 16; return v.f;
}
__device__ __forceinline__ u16 f2bf(float f) {            // RNE
  union { float f; u32 u; } v; v.f = f;
  u32 r = v.u + 0x7fffu + ((v.u >> 16) & 1u);
  return (u16)(r >> 16);
}
__device__ __forceinline__ u32 cvtpk_bf16(float a, float b) {  // lo16=bf16(a), hi16=bf16(b)
  u32 r;
  asm("v_cvt_pk_bf16_f32 %0, %1, %2" : "=v"(r) : "v"(a), "v"(b));
  return r;
}
// x = {a.lo32lanes, b.lo32lanes}, y = {a.hi32lanes, b.hi32lanes}
__device__ __forceinline__ void swap_halves(u32 a, u32 b, u32& x, u32& y) {
#if __has_builtin(__builtin_amdgcn_permlane32_swap)
  uintx2 r = __builtin_amdgcn_permlane32_swap(a, b, false, false);
  x = r.x; y = r.y;
#else
  u32 ax = (u32)__shfl_xor((int)a, 32);
  u32 bx = (u32)__shfl_xor((int)b, 32);
  bool h = (threadIdx.x & 32) != 0;
  x = h ? bx : a;
  y = h ? b : ax;
#endif
}

// ---------------- merged prep: wq split (bx<4608) + LayerNorm (bx>=4608) ----------------
__global__ __launch_bounds__(256) void k_pre(
    const float* __restrict__ wq1, const float* __restrict__ wq2,
    u16* __restrict__ wh, u16* __restrict__ wl,
    const float* __restrict__ x1, const float* __restrict__ x2,
    const float* __restrict__ g1, const float* __restrict__ b1,
    const float* __restrict__ g2, const float* __restrict__ b2,
    u16* __restrict__ xn_hi, u16* __restrict__ xn_lo)
{
  int bx = blockIdx.x;
  int t = threadIdx.x;
  if (bx < 4608) {
    // ---- prep_wq: split qkv weights fp32 -> bf16 hi/lo, permuted ----
    int modal = bx / 2304, rowp = bx % 2304;
    int typ = rowp / 768, hd = rowp % 768;
    const float* W = (modal ? wq2 : wq1) + (size_t)(hd * 3 + typ) * EMB;
    size_t dst = (size_t)bx * EMB;
    #pragma unroll
    for (int i = 0; i < 3; ++i) {
      int e = t + i * 256;
      float v = W[e];
      u16 h = f2bf(v);
      wh[dst + e] = h;
      wl[dst + e] = f2bf(v - bf2f(h));
    }
  } else {
    // ---- k_ln: LayerNorm (fp32 in) + hi/lo bf16 split ----
    int row = bx - 4608;                // 0..8191, modal-major
    int modal = row >> 12;
    const float* x = modal ? x2 : x1;
    const float* g = modal ? g2 : g1;
    const float* bb = modal ? b2 : b1;
    int r = row & (RPM - 1);
    const float* xr = x + (size_t)r * EMB;
    float v0 = xr[t], v1 = xr[t + 256], v2 = xr[t + 512];
    float s = v0 + v1 + v2;
    float s2 = v0 * v0 + v1 * v1 + v2 * v2;
    #pragma unroll
    for (int m = 1; m < 64; m <<= 1) { s += __shfl_xor(s, m); s2 += __shfl_xor(s2, m); }
    __shared__ float ls[4], ls2[4];
    int w = t >> 6;
    if ((t & 63) == 0) { ls[w] = s; ls2[w] = s2; }
    __syncthreads();
    s = ls[0] + ls[1] + ls[2] + ls[3];
    s2 = ls2[0] + ls2[1] + ls2[2] + ls2[3];
    float mu = s * (1.0f / EMB);
    float var = s2 * (1.0f / EMB) - mu * mu;
    float rs = rsqrtf(var + 1e-5f);
    size_t base = (size_t)row * EMB;
    float vv[3] = { v0, v1, v2 };
    #pragma unroll
    for (int i = 0; i < 3; ++i) {
      int e = t + i * 256;
      float xn = (vv[i] - mu) * rs * g[e] + bb[e];
      u16 h = f2bf(xn);
      xn_hi[base + e] = h;
      xn_lo[base + e] = f2bf(xn - bf2f(h));
    }
  }
}

// prep: w_proj fp32 -> bf16 hi only (runs after k_attn; wp_h aliases dead q_lo)
__global__ __launch_bounds__(256) void prep_wp(
    const float* __restrict__ wp1, const float* __restrict__ wp2,
    u16* __restrict__ wh)
{
  int bx = blockIdx.x;                  // 0..1535
  int modal = bx / 768, row = bx % 768;
  const float* W = (modal ? wp2 : wp1) + (size_t)row * EMB;
  size_t dst = (size_t)bx * EMB;
  int t = threadIdx.x;
  #pragma unroll
  for (int i = 0; i < 3; ++i) {
    int e = t + i * 256;
    wh[dst + e] = f2bf(W[e]);
  }
}

// ---------------- Kernel 2: QKV GEMM, 2-phase dbuf + counted vmcnt (r11 structure) ----
// grid (32 row-tiles, 18 col-tiles, 2 modals), 256 thr. Tile 128x128, BK=32.
// LDS [2][128][32] per operand; chunk swizzle f(r)=(r&3)^((r>>2)&3):
// LDS[r][j] = src[r][j ^ f(r)], read at j = lq ^ f(lc)  (2-way max read aliasing).
// Q output (typ==0) pre-scaled by CS_SCALE so k_attn's S arrives in log2 domain.
__global__ __launch_bounds__(256) void k_qkv(
    const u16* __restrict__ xn_hi, const u16* __restrict__ xn_lo,
    const u16* __restrict__ wqh, const u16* __restrict__ wql,
    const float* __restrict__ bq1, const float* __restrict__ bq2,
    u16* __restrict__ q_hi, u16* __restrict__ q_lo,
    u16* __restrict__ k_hi, u16* __restrict__ k_lo,
    u16* __restrict__ vT)
{
  int mt = blockIdx.x, ntile = blockIdx.y, modal = blockIdx.z;
  const float* BQ = modal ? bq2 : bq1;
  int typ = ntile / 6;            // 0=q 1=k 2=v
  int hd0 = (ntile % 6) * 128;

  __shared__ __align__(16) u16 As_hi[2][128 * 32], Wh[2][128 * 32],
                               As_lo[2][128 * 32], Wl[2][128 * 32];

  int tid = threadIdx.x, lane = tid & 63, w = tid >> 6;
  int wm = (w >> 1) * 64, wn = (w & 1) * 64;
  int lc = lane & 15, lq = lane >> 4;

  int srow = lane >> 2;                          // 0..15: row within 16-row segment
  int schunk = ((lane & 3) ^ (srow & 3) ^ ((srow >> 2) & 3)) << 3;  // pre-swizzled src chunk

  floatx4 acc[4][4] = {};
  const u16* aH = xn_hi + (size_t)(modal * RPM + mt * 128) * EMB;
  const u16* aL = xn_lo + (size_t)(modal * RPM + mt * 128) * EMB;
  const u16* wH = wqh + (size_t)(modal * 2304 + typ * 768 + hd0) * EMB;
  const u16* wL = wql + (size_t)(modal * 2304 + typ * 768 + hd0) * EMB;

  auto stage = [&](int buf, int k0) {
    if (typ != 2) {
      #pragma unroll
      for (int c = 0; c < 8; ++c) {
        int seg = w * 8 + c;                     // 0..31
        int tile = seg >> 3, segin = seg & 7;
        size_t off = (size_t)(segin * 16 + srow) * EMB + k0 + schunk;
        const u16* src; u16* dstb;
        if (tile == 0)      { src = aH + off; dstb = &As_hi[buf][0]; }
        else if (tile == 1) { src = wH + off; dstb = &Wh[buf][0]; }
        else if (tile == 2) { src = aL + off; dstb = &As_lo[buf][0]; }
        else                { src = wL + off; dstb = &Wl[buf][0]; }
        __builtin_amdgcn_global_load_lds(
            (const __attribute__((address_space(1))) unsigned int*)src,
            (__attribute__((address_space(3))) unsigned int*)(dstb + segin * 512), 16, 0, 0);
      }
    } else {
      #pragma unroll
      for (int c = 0; c < 4; ++c) {
        int seg = w * 4 + c;                     // 0..15
        int tile = seg >> 3, segin = seg & 7;
        size_t off = (size_t)(segin * 16 + srow) * EMB + k0 + schunk;
        const u16* src; u16* dstb;
        if (tile == 0) { src = aH + off; dstb = &As_hi[buf][0]; }
        else           { src = wH + off; dstb = &Wh[buf][0]; }
        __builtin_amdgcn_global_load_lds(
            (const __attribute__((address_space(1))) unsigned int*)src,
            (__attribute__((address_space(3))) unsigned int*)(dstb + segin * 512), 16, 0, 0);
      }
    }
  };

  stage(0, 0);
  for (int kk = 0; kk < 24; ++kk) {
    int cur = kk & 1;
    bool more = (kk + 1 < 24);
    if (more) stage(cur ^ 1, (kk + 1) * 32);
    // wait only the OLDER batch (cur buf); leave the just-issued prefetch in flight
    if (typ != 2) {
      if (more) asm volatile("s_waitcnt vmcnt(8)" ::: "memory");
      else      asm volatile("s_waitcnt vmcnt(0)" ::: "memory");
    } else {
      if (more) asm volatile("s_waitcnt vmcnt(4)" ::: "memory");
      else      asm volatile("s_waitcnt vmcnt(0)" ::: "memory");
    }
    __builtin_amdgcn_s_barrier();
    __builtin_amdgcn_sched_barrier(0);

    shortx8 ah[4], al[4], whf[4], wlf[4];
    int ca = (lq ^ (lc & 3) ^ ((lc >> 2) & 3)) << 3;  // swizzled read chunk (u16 units)
    #pragma unroll
    for (int i = 0; i < 4; ++i) {
      int ra = wm + i * 16 + lc, rw = wn + i * 16 + lc;
      ah[i]  = *(const shortx8*)&As_hi[cur][ra * 32 + ca];
      whf[i] = *(const shortx8*)&Wh[cur][rw * 32 + ca];
      if (typ != 2) {
        al[i]  = *(const shortx8*)&As_lo[cur][ra * 32 + ca];
        wlf[i] = *(const shortx8*)&Wl[cur][rw * 32 + ca];
      }
    }
    #pragma unroll
    for (int i = 0; i < 4; ++i)
      #pragma unroll
      for (int jn = 0; jn < 4; ++jn) {
        acc[i][jn] = __builtin_amdgcn_mfma_f32_16x16x32_bf16(ah[i], whf[jn], acc[i][jn], 0, 0, 0);
        if (typ != 2) {
          acc[i][jn] = __builtin_amdgcn_mfma_f32_16x16x32_bf16(al[i], whf[jn], acc[i][jn], 0, 0, 0);
          acc[i][jn] = __builtin_amdgcn_mfma_f32_16x16x32_bf16(ah[i], wlf[jn], acc[i][jn], 0, 0, 0);
        }
      }
    // ensure this wave's LDS reads are fully drained before signaling tile-done
    asm volatile("s_waitcnt lgkmcnt(0)" ::: "memory");
    __builtin_amdgcn_s_barrier();
    __builtin_amdgcn_sched_barrier(0);
  }

  #pragma unroll
  for (int i = 0; i < 4; ++i) {
    int mrow0 = mt * 128 + wm + i * 16 + lq * 4;
    #pragma unroll
    for (int jn = 0; jn < 4; ++jn) {
      int colp = hd0 + wn + jn * 16 + lc;          // hd index [0,768)
      int h = colp >> 6, d = colp & 63;
      float bias = BQ[colp * 3 + typ];
      #pragma unroll
      for (int r = 0; r < 4; ++r) {
        int mrow = mrow0 + r;
        int b = mrow >> 11, nq = mrow & (SEQ - 1);
        int uu = modal * 24 + b * 12 + h;
        float val = acc[i][jn][r] + bias;
        if (typ == 0) {
          val *= CS_SCALE;                       // pre-scale Q into log2-softmax domain
          size_t o = ((size_t)uu * SEQ + nq) * HDIM + d;
          u16 hh = f2bf(val); q_hi[o] = hh; q_lo[o] = f2bf(val - bf2f(hh));
        } else if (typ == 1) {
          size_t o = ((size_t)uu * SEQ + nq) * HDIM + d;
          u16 hh = f2bf(val); k_hi[o] = hh; k_lo[o] = f2bf(val - bf2f(hh));
        } else {
          vT[((size_t)uu * HDIM + d) * SEQ + nq] = f2bf(val);
        }
      }
    }
  }
}

// ---------------- Kernel 3: flash attention (r11 body, verified 121.5us) ----------
// grid (16,48) XCD-remapped (K/V L2-resident, FETCH 32MB). Q pre-scaled -> S in log2
// domain. Per-slice fused {exp2 -> lsum -> pack -> PV}.
__global__ __launch_bounds__(256, 3) void k_attn(
    const u16* __restrict__ q_hi, const u16* __restrict__ q_lo,
    const u16* __restrict__ k_hi, const u16* __restrict__ k_lo,
    const u16* __restrict__ vT, u16* __restrict__ attn_out)
{
  int id = blockIdx.x + (blockIdx.y << 4);       // 0..767
  int xcd = id & 7, j = id >> 3;                 // j: 0..95
  int u = xcd * 6 + (j >> 4);                    // 6 units per XCD
  int qt = j & 15;

  // [buf][tile]: tile 0 = K_hi [64k][64d], 1 = K_lo, 2 = V^T [64d][64k]; XOR-swizzled
  __shared__ __align__(16) u16 lds[2][3 * KTS];

  int tid = threadIdx.x, lane = tid & 63, w = tid >> 6;
  int col = lane & 31, hi = lane >> 5;
  int swz = (col & 7) << 4;              // read-side swizzle: row&7 == col&7 for all our reads

  // ---- Q fragments in regs: lane holds q = base+col, d = s*16 + hi*8 + 0..7 ----
  shortx8 qh[4], qlo[4];
  {
    size_t qb = ((size_t)u * SEQ + qt * 128 + w * 32 + col) * HDIM + hi * 8;
    #pragma unroll
    for (int s = 0; s < 4; ++s) {
      qh[s]  = *(const shortx8*)(q_hi + qb + s * 16);
      qlo[s] = *(const shortx8*)(q_lo + qb + s * 16);
    }
  }

  // ---- staging: 24 x 1KB segments via global_load_lds; source pre-swizzled ----
  int lrow = lane >> 3;                          // 0..7 (row within 8-row segment)
  int lcol = ((lane & 7) ^ lrow) << 3;           // swizzled elem offset within 64
  const u16* kh_src = k_hi + (size_t)u * SEQ * HDIM;
  const u16* kl_src = k_lo + (size_t)u * SEQ * HDIM;
  const u16* v_src  = vT  + (size_t)u * HDIM * SEQ;

  auto stage = [&](int buf, int kc) {
    #pragma unroll
    for (int c = 0; c < 6; ++c) {
      int seg = w * 6 + c;                       // 0..23, wave-uniform
      int tile = seg >> 3, segin = seg & 7;
      u16* dst = &lds[buf][tile * KTS + segin * 512];
      const u16* src;
      if (tile == 0)      src = kh_src + (size_t)(kc + segin * 8 + lrow) * HDIM + lcol;
      else if (tile == 1) src = kl_src + (size_t)(kc + segin * 8 + lrow) * HDIM + lcol;
      else                src = v_src  + (size_t)(segin * 8 + lrow) * SEQ + kc + lcol;
      __builtin_amdgcn_global_load_lds(
          (const __attribute__((address_space(1))) unsigned int*)src,
          (__attribute__((address_space(3))) unsigned int*)dst, 16, 0, 0);
    }
  };

  floatx16 O0 = {}, O1 = {};                     // O^T: lane col = d(+32*dt), regs = q (crow)
  float m_r = -1e30f, lsum = 0.0f;               // per-lane: q = col (log2 domain)
  const float THR = 8.0f;                        // defer-max threshold (log2 domain)

  stage(0, 0);
  __syncthreads();

  for (int t = 0; t < SEQ / 64; ++t) {
    int cur = t & 1;
    if (t + 1 < SEQ / 64) stage(cur ^ 1, (t + 1) * 64);

    const char* Kh = (const char*)&lds[cur][0];
    const char* Kl = (const char*)&lds[cur][KTS];
    const char* Vt = (const char*)&lds[cur][2 * KTS];

    // ---- swapped QK^T: S^T[k][q] in log2 domain (Q pre-scaled) ----
    floatx16 S0 = {}, S1 = {};
    __builtin_amdgcn_s_setprio(1);
    #pragma unroll
    for (int s = 0; s < 4; ++s) {
      int cb = (s * 32 + hi * 16) ^ swz;
      shortx8 kf0 = *(const shortx8*)(Kh + col * 128 + cb);
      shortx8 kl0 = *(const shortx8*)(Kl + col * 128 + cb);
      shortx8 kf1 = *(const shortx8*)(Kh + (32 + col) * 128 + cb);
      shortx8 kl1 = *(const shortx8*)(Kl + (32 + col) * 128 + cb);
      S0 = __builtin_amdgcn_mfma_f32_32x32x16_bf16(kf0, qh[s],  S0, 0, 0, 0);
      S1 = __builtin_amdgcn_mfma_f32_32x32x16_bf16(kf1, qh[s],  S1, 0, 0, 0);
      S0 = __builtin_amdgcn_mfma_f32_32x32x16_bf16(kf0, qlo[s], S0, 0, 0, 0);
      S1 = __builtin_amdgcn_mfma_f32_32x32x16_bf16(kf1, qlo[s], S1, 0, 0, 0);
      S0 = __builtin_amdgcn_mfma_f32_32x32x16_bf16(kl0, qh[s],  S0, 0, 0, 0);
      S1 = __builtin_amdgcn_mfma_f32_32x32x16_bf16(kl1, qh[s],  S1, 0, 0, 0);
    }
    __builtin_amdgcn_s_setprio(0);

    // ---- lane-local chunk max (tree, already log2-scaled), pair-reduce lane^32 ----
    float tm[16];
    #pragma unroll
    for (int r = 0; r < 16; ++r) tm[r] = fmaxf(S0[r], S1[r]);
    #pragma unroll
    for (int st = 8; st >= 1; st >>= 1)
      #pragma unroll
      for (int i = 0; i < st; ++i) tm[i] = fmaxf(tm[i], tm[i + st]);
    float mx = tm[0];
    mx = fmaxf(mx, __shfl_xor(mx, 32));

    // ---- defer-max rescale (T13): only when chunk max grows past m+THR ----
    if (!__all(mx <= m_r + THR)) {
      float mn = fmaxf(m_r, mx);
      float alpha = __builtin_amdgcn_exp2f(m_r - mn);
      m_r = mn;
      lsum *= alpha;
      #pragma unroll
      for (int r = 0; r < 16; ++r) {               // transpose alpha[q] into O lanes
        int qsrc = (r & 3) + 8 * (r >> 2) + 4 * hi;
        union { float f; int i; } a; a.f = alpha;
        a.i = __builtin_amdgcn_ds_bpermute(qsrc << 2, a.i);
        O0[r] *= a.f; O1[r] *= a.f;
      }
    }

    // ---- per-k-slice fused: exp2 -> lsum -> pack -> PV (MFMA/VALU interleave) ----
    __builtin_amdgcn_s_setprio(1);
    #pragma unroll
    for (int ks = 0; ks < 4; ++ks) {
      const int h2 = ks & 1;
      float ee[8];
      #pragma unroll
      for (int i = 0; i < 8; ++i) {
        float sv = (ks < 2) ? S0[h2 * 8 + i] : S1[h2 * 8 + i];
        ee[i] = __builtin_amdgcn_exp2f(sv - m_r);
      }
      lsum += ((ee[0] + ee[1]) + (ee[2] + ee[3])) + ((ee[4] + ee[5]) + (ee[6] + ee[7]));
      u32 A = cvtpk_bf16(ee[0], ee[1]);
      u32 B = cvtpk_bf16(ee[2], ee[3]);
      u32 C = cvtpk_bf16(ee[4], ee[5]);
      u32 D = cvtpk_bf16(ee[6], ee[7]);
      u32 w0, w1, w2, w3;
      swap_halves(A, C, w0, w2);
      swap_halves(B, D, w1, w3);
      union { u32 uu[4]; shortx8 ss; } pk_;
      pk_.uu[0] = w0; pk_.uu[1] = w1; pk_.uu[2] = w2; pk_.uu[3] = w3;
      int cb = (ks * 32 + hi * 16) ^ swz;
      shortx8 v0 = *(const shortx8*)(Vt + col * 128 + cb);
      shortx8 v1 = *(const shortx8*)(Vt + (32 + col) * 128 + cb);
      O0 = __builtin_amdgcn_mfma_f32_32x32x16_bf16(pk_.ss, v0, O0, 0, 0, 0);
      O1 = __builtin_amdgcn_mfma_f32_32x32x16_bf16(pk_.ss, v1, O1, 0, 0, 0);
    }
    __builtin_amdgcn_s_setprio(0);

    __syncthreads();   // drains vmcnt (next-buf DMA) + lgkm; all waves done reading cur
  }

  // ---- epilogue: l = pair-sum, transpose 1/l into O lanes, store ----
  float lt = lsum + __shfl_xor(lsum, 32);
  float rl = __builtin_amdgcn_rcpf(lt);
  int modal = u / 24, b = (u / 12) & 1, h = u % 12;
  size_t obase = ((size_t)(modal * RPM + b * SEQ + qt * 128 + w * 32)) * EMB + h * 64 + col;
  #pragma unroll
  for (int r = 0; r < 16; ++r) {
    int ql_ = (r & 3) + 8 * (r >> 2) + 4 * hi;     // q-local row of this reg
    union { float f; int i; } a; a.f = rl;
    a.i = __builtin_amdgcn_ds_bpermute(ql_ << 2, a.i);
    size_t ob = obase + (size_t)ql_ * EMB;
    attn_out[ob]      = f2bf(O0[r] * a.f);
    attn_out[ob + 32] = f2bf(O1[r] * a.f);
  }
}

// ---------------- Kernel 4: proj GEMM + bias + fp32 residual, 2-phase dbuf -------
// grid (64 row-tiles, 6 col-tiles, 2 modals), 256 thr. Tile 64x128, BK=32.
__global__ __launch_bounds__(256) void k_proj(
    const u16* __restrict__ ao, const u16* __restrict__ wph,
    const float* __restrict__ x1, const float* __restrict__ x2,
    const float* __restrict__ bp1, const float* __restrict__ bp2,
    float* __restrict__ out)
{
  int mt = blockIdx.x, ntile = blockIdx.y, modal = blockIdx.z;
  const float* BP = modal ? bp2 : bp1;
  const float* x  = modal ? x2 : x1;

  __shared__ __align__(16) u16 As[2][64 * 32], Ws[2][128 * 32];
  int tid = threadIdx.x, lane = tid & 63, w = tid >> 6;
  int wm = (w >> 1) * 32, wn = (w & 1) * 64;
  int lc = lane & 15, lq = lane >> 4;

  int srow = lane >> 2;                          // 0..15
  int schunk = ((lane & 3) ^ (srow & 3) ^ ((srow >> 2) & 3)) << 3;  // pre-swizzled src chunk

  floatx4 acc[2][4] = {};
  const u16* aP = ao  + (size_t)(modal * RPM + mt * 64) * EMB;
  const u16* wP = wph + (size_t)(modal * 768 + ntile * 128) * EMB;

  auto stage = [&](int buf, int k0) {
    #pragma unroll
    for (int c = 0; c < 3; ++c) {
      int seg = w * 3 + c;                       // 0..11: 0..3 = As, 4..11 = Ws
      const u16* src; u16* dst;
      if (seg < 4) {
        src = aP + (size_t)(seg * 16 + srow) * EMB + k0 + schunk;
        dst = &As[buf][0] + seg * 512;
      } else {
        int s2 = seg - 4;
        src = wP + (size_t)(s2 * 16 + srow) * EMB + k0 + schunk;
        dst = &Ws[buf][0] + s2 * 512;
      }
      __builtin_amdgcn_global_load_lds(
          (const __attribute__((address_space(1))) unsigned int*)src,
          (__attribute__((address_space(3))) unsigned int*)dst, 16, 0, 0);
    }
  };

  stage(0, 0);
  for (int kk = 0; kk < 24; ++kk) {
    int cur = kk & 1;
    bool more = (kk + 1 < 24);
    if (more) stage(cur ^ 1, (kk + 1) * 32);
    if (more) asm volatile("s_waitcnt vmcnt(3)" ::: "memory");
    else      asm volatile("s_waitcnt vmcnt(0)" ::: "memory");
    __builtin_amdgcn_s_barrier();
    __builtin_amdgcn_sched_barrier(0);

    int ca = (lq ^ (lc & 3) ^ ((lc >> 2) & 3)) << 3;
    shortx8 af[2], wf[4];
    #pragma unroll
    for (int i = 0; i < 2; ++i) af[i] = *(const shortx8*)&As[cur][(wm + i * 16 + lc) * 32 + ca];
    #pragma unroll
    for (int i = 0; i < 4; ++i) wf[i] = *(const shortx8*)&Ws[cur][(wn + i * 16 + lc) * 32 + ca];
    #pragma unroll
    for (int i = 0; i < 2; ++i)
      #pragma unroll
      for (int jn = 0; jn < 4; ++jn)
        acc[i][jn] = __builtin_amdgcn_mfma_f32_16x16x32_bf16(af[i], wf[jn], acc[i][jn], 0, 0, 0);
    asm volatile("s_waitcnt lgkmcnt(0)" ::: "memory");
    __builtin_amdgcn_s_barrier();
    __builtin_amdgcn_sched_barrier(0);
  }

  #pragma unroll
  for (int i = 0; i < 2; ++i) {
    int mrow0 = mt * 64 + wm + i * 16 + lq * 4;
    #pragma unroll
    for (int jn = 0; jn < 4; ++jn) {
      int col = ntile * 128 + wn + jn * 16 + lc;
      float bias = BP[col];
      #pragma unroll
      for (int r = 0; r < 4; ++r) {
        int mrow = mrow0 + r;
        float val = acc[i][jn][r] + bias + x[(size_t)mrow * EMB + col];
        out[((size_t)(modal * RPM + mrow)) * EMB + col] = val;
      }
    }
  }
}

extern "C" void kernel_launch(void* const* d_in, const int* in_sizes, int n_in,
                              void* d_out, int out_size, void* d_ws, size_t ws_size,
                              hipStream_t stream) {
  const float* modal1 = (const float*)d_in[0];
  const float* modal2 = (const float*)d_in[1];
  const float* ln1_g  = (const float*)d_in[2];
  const float* ln1_b  = (const float*)d_in[3];
  const float* w_qkv1 = (const float*)d_in[4];
  const float* b_qkv1 = (const float*)d_in[5];
  const float* w_proj1= (const float*)d_in[6];
  const float* b_proj1= (const float*)d_in[7];
  const float* ln2_g  = (const float*)d_in[8];
  const float* ln2_b  = (const float*)d_in[9];
  const float* w_qkv2 = (const float*)d_in[10];
  const float* b_qkv2 = (const float*)d_in[11];
  const float* w_proj2= (const float*)d_in[12];
  const float* b_proj2= (const float*)d_in[13];
  float* out = (float*)d_out;

  const size_t BUFE = (size_t)NROW * EMB;       // 6291456 elems
  const size_t WQE  = (size_t)2 * 2304 * EMB;   // 3538944 elems
  u16* xn_hi = (u16*)d_ws;
  u16* xn_lo = xn_hi + BUFE;
  u16* q_hi  = xn_lo + BUFE;
  u16* q_lo  = q_hi + BUFE;
  u16* k_hi  = q_lo + BUFE;
  u16* k_lo  = k_hi + BUFE;
  u16* vT    = k_lo + BUFE;
  u16* wq_h  = vT + BUFE;
  u16* wq_l  = wq_h + WQE;
  u16* attn  = xn_hi;   // xn dead after k_qkv
  u16* wp_h  = q_lo;    // q_lo dead after k_attn (w_proj needs 1.18M < 6.29M elems)

  k_pre<<<4608 + NROW, 256, 0, stream>>>(w_qkv1, w_qkv2, wq_h, wq_l,
                                         modal1, modal2, ln1_g, ln1_b, ln2_g, ln2_b,
                                         xn_hi, xn_lo);
  dim3 g2(32, 18, 2);
  k_qkv<<<g2, 256, 0, stream>>>(xn_hi, xn_lo, wq_h, wq_l, b_qkv1, b_qkv2,
                                q_hi, q_lo, k_hi, k_lo, vT);
  dim3 g3(16, 48);
  k_attn<<<g3, 256, 0, stream>>>(q_hi, q_lo, k_hi, k_lo, vT, attn);
  prep_wp<<<1536, 256, 0, stream>>>(w_proj1, w_proj2, wp_h);
  dim3 g4(64, 6, 2);
  k_proj<<<g4, 256, 0, stream>>>(attn, wp_h, modal1, modal2, b_proj1, b_proj2, out);
}

// Round 11
// 343.431 us; speedup vs baseline: 1.2727x; 1.0338x over previous
//
#include <hip/hip_runtime.h>
#include <hip/hip_bf16.h>

// r11: 345.2us best. r12/r13/r14 k_qkv bets all failed/neutral -> 2-phase GEMM confirmed
//      phase-overhead-bound (m252 pattern); 8-phase rewrite too risky for remaining budget.
// r15: consolidate to r11-exact (original f(r)=r&3 swizzle) + fold prep_wp into k_pre when
//      ws_size permits a separate wp region (removes one launch); runtime fallback = r11.

typedef unsigned short u16;
typedef unsigned int   u32;
typedef __attribute__((ext_vector_type(4)))  float floatx4;
typedef __attribute__((ext_vector_type(16))) float floatx16;
typedef __attribute__((ext_vector_type(8)))  short shortx8;
typedef __attribute__((ext_vector_type(2)))  unsigned int uintx2;

#define EMB   768
#define SEQ   2048
#define NHEAD 12
#define HDIM  64
#define RPM   4096   // rows per modal (B*N)
#define NROW  8192   // total rows (2 modals)
#define NUNIT 48     // modal*B*H units
#define KTS   4096   // attn LDS tile elems (64*64)
#define CS_SCALE 11.5415603271f   // 8 * log2(e)

__device__ __forceinline__ float bf2f(u16 h) {
  union { u32 u; float f; } v; v.u = ((u32)h) << 16; return v.f;
}
__device__ __forceinline__ u16 f2bf(float f) {            // RNE
  union { float f; u32 u; } v; v.f = f;
  u32 r = v.u + 0x7fffu + ((v.u >> 16) & 1u);
  return (u16)(r >> 16);
}
__device__ __forceinline__ u32 cvtpk_bf16(float a, float b) {  // lo16=bf16(a), hi16=bf16(b)
  u32 r;
  asm("v_cvt_pk_bf16_f32 %0, %1, %2" : "=v"(r) : "v"(a), "v"(b));
  return r;
}
// x = {a.lo32lanes, b.lo32lanes}, y = {a.hi32lanes, b.hi32lanes}
__device__ __forceinline__ void swap_halves(u32 a, u32 b, u32& x, u32& y) {
#if __has_builtin(__builtin_amdgcn_permlane32_swap)
  uintx2 r = __builtin_amdgcn_permlane32_swap(a, b, false, false);
  x = r.x; y = r.y;
#else
  u32 ax = (u32)__shfl_xor((int)a, 32);
  u32 bx = (u32)__shfl_xor((int)b, 32);
  bool h = (threadIdx.x & 32) != 0;
  x = h ? bx : a;
  y = h ? b : ax;
#endif
}

// ---------------- merged prep: wq split + LayerNorm (+ optional wp split) ----------------
// bx < 4608: wq hi/lo split; bx < 4608+NROW: LayerNorm; else (merged mode): wp split.
__global__ __launch_bounds__(256) void k_pre(
    const float* __restrict__ wq1, const float* __restrict__ wq2,
    u16* __restrict__ wh, u16* __restrict__ wl,
    const float* __restrict__ x1, const float* __restrict__ x2,
    const float* __restrict__ g1, const float* __restrict__ b1,
    const float* __restrict__ g2, const float* __restrict__ b2,
    u16* __restrict__ xn_hi, u16* __restrict__ xn_lo,
    const float* __restrict__ wp1, const float* __restrict__ wp2,
    u16* __restrict__ wph)
{
  int bx = blockIdx.x;
  int t = threadIdx.x;
  if (bx < 4608) {
    // ---- prep_wq: split qkv weights fp32 -> bf16 hi/lo, permuted ----
    int modal = bx / 2304, rowp = bx % 2304;
    int typ = rowp / 768, hd = rowp % 768;
    const float* W = (modal ? wq2 : wq1) + (size_t)(hd * 3 + typ) * EMB;
    size_t dst = (size_t)bx * EMB;
    #pragma unroll
    for (int i = 0; i < 3; ++i) {
      int e = t + i * 256;
      float v = W[e];
      u16 h = f2bf(v);
      wh[dst + e] = h;
      wl[dst + e] = f2bf(v - bf2f(h));
    }
  } else if (bx < 4608 + NROW) {
    // ---- k_ln: LayerNorm (fp32 in) + hi/lo bf16 split ----
    int row = bx - 4608;                // 0..8191, modal-major
    int modal = row >> 12;
    const float* x = modal ? x2 : x1;
    const float* g = modal ? g2 : g1;
    const float* bb = modal ? b2 : b1;
    int r = row & (RPM - 1);
    const float* xr = x + (size_t)r * EMB;
    float v0 = xr[t], v1 = xr[t + 256], v2 = xr[t + 512];
    float s = v0 + v1 + v2;
    float s2 = v0 * v0 + v1 * v1 + v2 * v2;
    #pragma unroll
    for (int m = 1; m < 64; m <<= 1) { s += __shfl_xor(s, m); s2 += __shfl_xor(s2, m); }
    __shared__ float ls[4], ls2[4];
    int w = t >> 6;
    if ((t & 63) == 0) { ls[w] = s; ls2[w] = s2; }
    __syncthreads();
    s = ls[0] + ls[1] + ls[2] + ls[3];
    s2 = ls2[0] + ls2[1] + ls2[2] + ls2[3];
    float mu = s * (1.0f / EMB);
    float var = s2 * (1.0f / EMB) - mu * mu;
    float rs = rsqrtf(var + 1e-5f);
    size_t base = (size_t)row * EMB;
    float vv[3] = { v0, v1, v2 };
    #pragma unroll
    for (int i = 0; i < 3; ++i) {
      int e = t + i * 256;
      float xn = (vv[i] - mu) * rs * g[e] + bb[e];
      u16 h = f2bf(xn);
      xn_hi[base + e] = h;
      xn_lo[base + e] = f2bf(xn - bf2f(h));
    }
  } else {
    // ---- prep_wp: w_proj fp32 -> bf16 hi (merged mode only) ----
    int px = bx - (4608 + NROW);        // 0..1535
    int modal = px / 768, row = px % 768;
    const float* W = (modal ? wp2 : wp1) + (size_t)row * EMB;
    size_t dst = (size_t)px * EMB;
    #pragma unroll
    for (int i = 0; i < 3; ++i) {
      int e = t + i * 256;
      wph[dst + e] = f2bf(W[e]);
    }
  }
}

// prep: w_proj fp32 -> bf16 hi only (fallback path; wp aliases dead q_lo)
__global__ __launch_bounds__(256) void prep_wp(
    const float* __restrict__ wp1, const float* __restrict__ wp2,
    u16* __restrict__ wh)
{
  int bx = blockIdx.x;                  // 0..1535
  int modal = bx / 768, row = bx % 768;
  const float* W = (modal ? wp2 : wp1) + (size_t)row * EMB;
  size_t dst = (size_t)bx * EMB;
  int t = threadIdx.x;
  #pragma unroll
  for (int i = 0; i < 3; ++i) {
    int e = t + i * 256;
    wh[dst + e] = f2bf(W[e]);
  }
}

// ---------------- Kernel 2: QKV GEMM, 2-phase dbuf + counted vmcnt (r11 structure) ----
// grid (32 row-tiles, 18 col-tiles, 2 modals), 256 thr. Tile 128x128, BK=32.
// LDS [2][128][32] per operand, 2-bit chunk XOR swizzle: LDS[r][j] = src[r][j^(r&3)].
// Q output (typ==0) pre-scaled by CS_SCALE so k_attn's S arrives in log2 domain.
__global__ __launch_bounds__(256) void k_qkv(
    const u16* __restrict__ xn_hi, const u16* __restrict__ xn_lo,
    const u16* __restrict__ wqh, const u16* __restrict__ wql,
    const float* __restrict__ bq1, const float* __restrict__ bq2,
    u16* __restrict__ q_hi, u16* __restrict__ q_lo,
    u16* __restrict__ k_hi, u16* __restrict__ k_lo,
    u16* __restrict__ vT)
{
  int mt = blockIdx.x, ntile = blockIdx.y, modal = blockIdx.z;
  const float* BQ = modal ? bq2 : bq1;
  int typ = ntile / 6;            // 0=q 1=k 2=v
  int hd0 = (ntile % 6) * 128;

  __shared__ __align__(16) u16 As_hi[2][128 * 32], Wh[2][128 * 32],
                               As_lo[2][128 * 32], Wl[2][128 * 32];

  int tid = threadIdx.x, lane = tid & 63, w = tid >> 6;
  int wm = (w >> 1) * 64, wn = (w & 1) * 64;
  int lc = lane & 15, lq = lane >> 4;

  int srow = lane >> 2;                          // 0..15: row within 16-row segment
  int schunk = ((lane & 3) ^ (srow & 3)) << 3;   // pre-swizzled source chunk (u16 units)

  floatx4 acc[4][4] = {};
  const u16* aH = xn_hi + (size_t)(modal * RPM + mt * 128) * EMB;
  const u16* aL = xn_lo + (size_t)(modal * RPM + mt * 128) * EMB;
  const u16* wH = wqh + (size_t)(modal * 2304 + typ * 768 + hd0) * EMB;
  const u16* wL = wql + (size_t)(modal * 2304 + typ * 768 + hd0) * EMB;

  auto stage = [&](int buf, int k0) {
    if (typ != 2) {
      #pragma unroll
      for (int c = 0; c < 8; ++c) {
        int seg = w * 8 + c;                     // 0..31
        int tile = seg >> 3, segin = seg & 7;
        size_t off = (size_t)(segin * 16 + srow) * EMB + k0 + schunk;
        const u16* src; u16* dstb;
        if (tile == 0)      { src = aH + off; dstb = &As_hi[buf][0]; }
        else if (tile == 1) { src = wH + off; dstb = &Wh[buf][0]; }
        else if (tile == 2) { src = aL + off; dstb = &As_lo[buf][0]; }
        else                { src = wL + off; dstb = &Wl[buf][0]; }
        __builtin_amdgcn_global_load_lds(
            (const __attribute__((address_space(1))) unsigned int*)src,
            (__attribute__((address_space(3))) unsigned int*)(dstb + segin * 512), 16, 0, 0);
      }
    } else {
      #pragma unroll
      for (int c = 0; c < 4; ++c) {
        int seg = w * 4 + c;                     // 0..15
        int tile = seg >> 3, segin = seg & 7;
        size_t off = (size_t)(segin * 16 + srow) * EMB + k0 + schunk;
        const u16* src; u16* dstb;
        if (tile == 0) { src = aH + off; dstb = &As_hi[buf][0]; }
        else           { src = wH + off; dstb = &Wh[buf][0]; }
        __builtin_amdgcn_global_load_lds(
            (const __attribute__((address_space(1))) unsigned int*)src,
            (__attribute__((address_space(3))) unsigned int*)(dstb + segin * 512), 16, 0, 0);
      }
    }
  };

  stage(0, 0);
  for (int kk = 0; kk < 24; ++kk) {
    int cur = kk & 1;
    bool more = (kk + 1 < 24);
    if (more) stage(cur ^ 1, (kk + 1) * 32);
    // wait only the OLDER batch (cur buf); leave the just-issued prefetch in flight
    if (typ != 2) {
      if (more) asm volatile("s_waitcnt vmcnt(8)" ::: "memory");
      else      asm volatile("s_waitcnt vmcnt(0)" ::: "memory");
    } else {
      if (more) asm volatile("s_waitcnt vmcnt(4)" ::: "memory");
      else      asm volatile("s_waitcnt vmcnt(0)" ::: "memory");
    }
    __builtin_amdgcn_s_barrier();
    __builtin_amdgcn_sched_barrier(0);

    shortx8 ah[4], al[4], whf[4], wlf[4];
    int ca = (lq ^ (lc & 3)) << 3;               // swizzled read chunk (u16 units)
    #pragma unroll
    for (int i = 0; i < 4; ++i) {
      int ra = wm + i * 16 + lc, rw = wn + i * 16 + lc;
      ah[i]  = *(const shortx8*)&As_hi[cur][ra * 32 + ca];
      whf[i] = *(const shortx8*)&Wh[cur][rw * 32 + ca];
      if (typ != 2) {
        al[i]  = *(const shortx8*)&As_lo[cur][ra * 32 + ca];
        wlf[i] = *(const shortx8*)&Wl[cur][rw * 32 + ca];
      }
    }
    #pragma unroll
    for (int i = 0; i < 4; ++i)
      #pragma unroll
      for (int jn = 0; jn < 4; ++jn) {
        acc[i][jn] = __builtin_amdgcn_mfma_f32_16x16x32_bf16(ah[i], whf[jn], acc[i][jn], 0, 0, 0);
        if (typ != 2) {
          acc[i][jn] = __builtin_amdgcn_mfma_f32_16x16x32_bf16(al[i], whf[jn], acc[i][jn], 0, 0, 0);
          acc[i][jn] = __builtin_amdgcn_mfma_f32_16x16x32_bf16(ah[i], wlf[jn], acc[i][jn], 0, 0, 0);
        }
      }
    // ensure this wave's LDS reads are fully drained before signaling tile-done
    asm volatile("s_waitcnt lgkmcnt(0)" ::: "memory");
    __builtin_amdgcn_s_barrier();
    __builtin_amdgcn_sched_barrier(0);
  }

  #pragma unroll
  for (int i = 0; i < 4; ++i) {
    int mrow0 = mt * 128 + wm + i * 16 + lq * 4;
    #pragma unroll
    for (int jn = 0; jn < 4; ++jn) {
      int colp = hd0 + wn + jn * 16 + lc;          // hd index [0,768)
      int h = colp >> 6, d = colp & 63;
      float bias = BQ[colp * 3 + typ];
      #pragma unroll
      for (int r = 0; r < 4; ++r) {
        int mrow = mrow0 + r;
        int b = mrow >> 11, nq = mrow & (SEQ - 1);
        int uu = modal * 24 + b * 12 + h;
        float val = acc[i][jn][r] + bias;
        if (typ == 0) {
          val *= CS_SCALE;                       // pre-scale Q into log2-softmax domain
          size_t o = ((size_t)uu * SEQ + nq) * HDIM + d;
          u16 hh = f2bf(val); q_hi[o] = hh; q_lo[o] = f2bf(val - bf2f(hh));
        } else if (typ == 1) {
          size_t o = ((size_t)uu * SEQ + nq) * HDIM + d;
          u16 hh = f2bf(val); k_hi[o] = hh; k_lo[o] = f2bf(val - bf2f(hh));
        } else {
          vT[((size_t)uu * HDIM + d) * SEQ + nq] = f2bf(val);
        }
      }
    }
  }
}

// ---------------- Kernel 3: flash attention (r11 body, verified 121.5us) ----------
// grid (16,48) XCD-remapped (K/V L2-resident, FETCH 32MB). Q pre-scaled -> S in log2
// domain. Per-slice fused {exp2 -> lsum -> pack -> PV}.
__global__ __launch_bounds__(256, 3) void k_attn(
    const u16* __restrict__ q_hi, const u16* __restrict__ q_lo,
    const u16* __restrict__ k_hi, const u16* __restrict__ k_lo,
    const u16* __restrict__ vT, u16* __restrict__ attn_out)
{
  int id = blockIdx.x + (blockIdx.y << 4);       // 0..767
  int xcd = id & 7, j = id >> 3;                 // j: 0..95
  int u = xcd * 6 + (j >> 4);                    // 6 units per XCD
  int qt = j & 15;

  // [buf][tile]: tile 0 = K_hi [64k][64d], 1 = K_lo, 2 = V^T [64d][64k]; XOR-swizzled
  __shared__ __align__(16) u16 lds[2][3 * KTS];

  int tid = threadIdx.x, lane = tid & 63, w = tid >> 6;
  int col = lane & 31, hi = lane >> 5;
  int swz = (col & 7) << 4;              // read-side swizzle: row&7 == col&7 for all our reads

  // ---- Q fragments in regs: lane holds q = base+col, d = s*16 + hi*8 + 0..7 ----
  shortx8 qh[4], qlo[4];
  {
    size_t qb = ((size_t)u * SEQ + qt * 128 + w * 32 + col) * HDIM + hi * 8;
    #pragma unroll
    for (int s = 0; s < 4; ++s) {
      qh[s]  = *(const shortx8*)(q_hi + qb + s * 16);
      qlo[s] = *(const shortx8*)(q_lo + qb + s * 16);
    }
  }

  // ---- staging: 24 x 1KB segments via global_load_lds; source pre-swizzled ----
  int lrow = lane >> 3;                          // 0..7 (row within 8-row segment)
  int lcol = ((lane & 7) ^ lrow) << 3;           // swizzled elem offset within 64
  const u16* kh_src = k_hi + (size_t)u * SEQ * HDIM;
  const u16* kl_src = k_lo + (size_t)u * SEQ * HDIM;
  const u16* v_src  = vT  + (size_t)u * HDIM * SEQ;

  auto stage = [&](int buf, int kc) {
    #pragma unroll
    for (int c = 0; c < 6; ++c) {
      int seg = w * 6 + c;                       // 0..23, wave-uniform
      int tile = seg >> 3, segin = seg & 7;
      u16* dst = &lds[buf][tile * KTS + segin * 512];
      const u16* src;
      if (tile == 0)      src = kh_src + (size_t)(kc + segin * 8 + lrow) * HDIM + lcol;
      else if (tile == 1) src = kl_src + (size_t)(kc + segin * 8 + lrow) * HDIM + lcol;
      else                src = v_src  + (size_t)(segin * 8 + lrow) * SEQ + kc + lcol;
      __builtin_amdgcn_global_load_lds(
          (const __attribute__((address_space(1))) unsigned int*)src,
          (__attribute__((address_space(3))) unsigned int*)dst, 16, 0, 0);
    }
  };

  floatx16 O0 = {}, O1 = {};                     // O^T: lane col = d(+32*dt), regs = q (crow)
  float m_r = -1e30f, lsum = 0.0f;               // per-lane: q = col (log2 domain)
  const float THR = 8.0f;                        // defer-max threshold (log2 domain)

  stage(0, 0);
  __syncthreads();

  for (int t = 0; t < SEQ / 64; ++t) {
    int cur = t & 1;
    if (t + 1 < SEQ / 64) stage(cur ^ 1, (t + 1) * 64);

    const char* Kh = (const char*)&lds[cur][0];
    const char* Kl = (const char*)&lds[cur][KTS];
    const char* Vt = (const char*)&lds[cur][2 * KTS];

    // ---- swapped QK^T: S^T[k][q] in log2 domain (Q pre-scaled) ----
    floatx16 S0 = {}, S1 = {};
    __builtin_amdgcn_s_setprio(1);
    #pragma unroll
    for (int s = 0; s < 4; ++s) {
      int cb = (s * 32 + hi * 16) ^ swz;
      shortx8 kf0 = *(const shortx8*)(Kh + col * 128 + cb);
      shortx8 kl0 = *(const shortx8*)(Kl + col * 128 + cb);
      shortx8 kf1 = *(const shortx8*)(Kh + (32 + col) * 128 + cb);
      shortx8 kl1 = *(const shortx8*)(Kl + (32 + col) * 128 + cb);
      S0 = __builtin_amdgcn_mfma_f32_32x32x16_bf16(kf0, qh[s],  S0, 0, 0, 0);
      S1 = __builtin_amdgcn_mfma_f32_32x32x16_bf16(kf1, qh[s],  S1, 0, 0, 0);
      S0 = __builtin_amdgcn_mfma_f32_32x32x16_bf16(kf0, qlo[s], S0, 0, 0, 0);
      S1 = __builtin_amdgcn_mfma_f32_32x32x16_bf16(kf1, qlo[s], S1, 0, 0, 0);
      S0 = __builtin_amdgcn_mfma_f32_32x32x16_bf16(kl0, qh[s],  S0, 0, 0, 0);
      S1 = __builtin_amdgcn_mfma_f32_32x32x16_bf16(kl1, qh[s],  S1, 0, 0, 0);
    }
    __builtin_amdgcn_s_setprio(0);

    // ---- lane-local chunk max (tree, already log2-scaled), pair-reduce lane^32 ----
    float tm[16];
    #pragma unroll
    for (int r = 0; r < 16; ++r) tm[r] = fmaxf(S0[r], S1[r]);
    #pragma unroll
    for (int st = 8; st >= 1; st >>= 1)
      #pragma unroll
      for (int i = 0; i < st; ++i) tm[i] = fmaxf(tm[i], tm[i + st]);
    float mx = tm[0];
    mx = fmaxf(mx, __shfl_xor(mx, 32));

    // ---- defer-max rescale (T13): only when chunk max grows past m+THR ----
    if (!__all(mx <= m_r + THR)) {
      float mn = fmaxf(m_r, mx);
      float alpha = __builtin_amdgcn_exp2f(m_r - mn);
      m_r = mn;
      lsum *= alpha;
      #pragma unroll
      for (int r = 0; r < 16; ++r) {               // transpose alpha[q] into O lanes
        int qsrc = (r & 3) + 8 * (r >> 2) + 4 * hi;
        union { float f; int i; } a; a.f = alpha;
        a.i = __builtin_amdgcn_ds_bpermute(qsrc << 2, a.i);
        O0[r] *= a.f; O1[r] *= a.f;
      }
    }

    // ---- per-k-slice fused: exp2 -> lsum -> pack -> PV (MFMA/VALU interleave) ----
    __builtin_amdgcn_s_setprio(1);
    #pragma unroll
    for (int ks = 0; ks < 4; ++ks) {
      const int h2 = ks & 1;
      float ee[8];
      #pragma unroll
      for (int i = 0; i < 8; ++i) {
        float sv = (ks < 2) ? S0[h2 * 8 + i] : S1[h2 * 8 + i];
        ee[i] = __builtin_amdgcn_exp2f(sv - m_r);
      }
      lsum += ((ee[0] + ee[1]) + (ee[2] + ee[3])) + ((ee[4] + ee[5]) + (ee[6] + ee[7]));
      u32 A = cvtpk_bf16(ee[0], ee[1]);
      u32 B = cvtpk_bf16(ee[2], ee[3]);
      u32 C = cvtpk_bf16(ee[4], ee[5]);
      u32 D = cvtpk_bf16(ee[6], ee[7]);
      u32 w0, w1, w2, w3;
      swap_halves(A, C, w0, w2);
      swap_halves(B, D, w1, w3);
      union { u32 uu[4]; shortx8 ss; } pk_;
      pk_.uu[0] = w0; pk_.uu[1] = w1; pk_.uu[2] = w2; pk_.uu[3] = w3;
      int cb = (ks * 32 + hi * 16) ^ swz;
      shortx8 v0 = *(const shortx8*)(Vt + col * 128 + cb);
      shortx8 v1 = *(const shortx8*)(Vt + (32 + col) * 128 + cb);
      O0 = __builtin_amdgcn_mfma_f32_32x32x16_bf16(pk_.ss, v0, O0, 0, 0, 0);
      O1 = __builtin_amdgcn_mfma_f32_32x32x16_bf16(pk_.ss, v1, O1, 0, 0, 0);
    }
    __builtin_amdgcn_s_setprio(0);

    __syncthreads();   // drains vmcnt (next-buf DMA) + lgkm; all waves done reading cur
  }

  // ---- epilogue: l = pair-sum, transpose 1/l into O lanes, store ----
  float lt = lsum + __shfl_xor(lsum, 32);
  float rl = __builtin_amdgcn_rcpf(lt);
  int modal = u / 24, b = (u / 12) & 1, h = u % 12;
  size_t obase = ((size_t)(modal * RPM + b * SEQ + qt * 128 + w * 32)) * EMB + h * 64 + col;
  #pragma unroll
  for (int r = 0; r < 16; ++r) {
    int ql_ = (r & 3) + 8 * (r >> 2) + 4 * hi;     // q-local row of this reg
    union { float f; int i; } a; a.f = rl;
    a.i = __builtin_amdgcn_ds_bpermute(ql_ << 2, a.i);
    size_t ob = obase + (size_t)ql_ * EMB;
    attn_out[ob]      = f2bf(O0[r] * a.f);
    attn_out[ob + 32] = f2bf(O1[r] * a.f);
  }
}

// ---------------- Kernel 4: proj GEMM + bias + fp32 residual, 2-phase dbuf -------
// grid (64 row-tiles, 6 col-tiles, 2 modals), 256 thr. Tile 64x128, BK=32.
__global__ __launch_bounds__(256) void k_proj(
    const u16* __restrict__ ao, const u16* __restrict__ wph,
    const float* __restrict__ x1, const float* __restrict__ x2,
    const float* __restrict__ bp1, const float* __restrict__ bp2,
    float* __restrict__ out)
{
  int mt = blockIdx.x, ntile = blockIdx.y, modal = blockIdx.z;
  const float* BP = modal ? bp2 : bp1;
  const float* x  = modal ? x2 : x1;

  __shared__ __align__(16) u16 As[2][64 * 32], Ws[2][128 * 32];
  int tid = threadIdx.x, lane = tid & 63, w = tid >> 6;
  int wm = (w >> 1) * 32, wn = (w & 1) * 64;
  int lc = lane & 15, lq = lane >> 4;

  int srow = lane >> 2;                          // 0..15
  int schunk = ((lane & 3) ^ (srow & 3)) << 3;   // pre-swizzled source chunk

  floatx4 acc[2][4] = {};
  const u16* aP = ao  + (size_t)(modal * RPM + mt * 64) * EMB;
  const u16* wP = wph + (size_t)(modal * 768 + ntile * 128) * EMB;

  auto stage = [&](int buf, int k0) {
    #pragma unroll
    for (int c = 0; c < 3; ++c) {
      int seg = w * 3 + c;                       // 0..11: 0..3 = As, 4..11 = Ws
      const u16* src; u16* dst;
      if (seg < 4) {
        src = aP + (size_t)(seg * 16 + srow) * EMB + k0 + schunk;
        dst = &As[buf][0] + seg * 512;
      } else {
        int s2 = seg - 4;
        src = wP + (size_t)(s2 * 16 + srow) * EMB + k0 + schunk;
        dst = &Ws[buf][0] + s2 * 512;
      }
      __builtin_amdgcn_global_load_lds(
          (const __attribute__((address_space(1))) unsigned int*)src,
          (__attribute__((address_space(3))) unsigned int*)dst, 16, 0, 0);
    }
  };

  stage(0, 0);
  for (int kk = 0; kk < 24; ++kk) {
    int cur = kk & 1;
    bool more = (kk + 1 < 24);
    if (more) stage(cur ^ 1, (kk + 1) * 32);
    if (more) asm volatile("s_waitcnt vmcnt(3)" ::: "memory");
    else      asm volatile("s_waitcnt vmcnt(0)" ::: "memory");
    __builtin_amdgcn_s_barrier();
    __builtin_amdgcn_sched_barrier(0);

    int ca = (lq ^ (lc & 3)) << 3;
    shortx8 af[2], wf[4];
    #pragma unroll
    for (int i = 0; i < 2; ++i) af[i] = *(const shortx8*)&As[cur][(wm + i * 16 + lc) * 32 + ca];
    #pragma unroll
    for (int i = 0; i < 4; ++i) wf[i] = *(const shortx8*)&Ws[cur][(wn + i * 16 + lc) * 32 + ca];
    #pragma unroll
    for (int i = 0; i < 2; ++i)
      #pragma unroll
      for (int jn = 0; jn < 4; ++jn)
        acc[i][jn] = __builtin_amdgcn_mfma_f32_16x16x32_bf16(af[i], wf[jn], acc[i][jn], 0, 0, 0);
    asm volatile("s_waitcnt lgkmcnt(0)" ::: "memory");
    __builtin_amdgcn_s_barrier();
    __builtin_amdgcn_sched_barrier(0);
  }

  #pragma unroll
  for (int i = 0; i < 2; ++i) {
    int mrow0 = mt * 64 + wm + i * 16 + lq * 4;
    #pragma unroll
    for (int jn = 0; jn < 4; ++jn) {
      int col = ntile * 128 + wn + jn * 16 + lc;
      float bias = BP[col];
      #pragma unroll
      for (int r = 0; r < 4; ++r) {
        int mrow = mrow0 + r;
        float val = acc[i][jn][r] + bias + x[(size_t)mrow * EMB + col];
        out[((size_t)(modal * RPM + mrow)) * EMB + col] = val;
      }
    }
  }
}

extern "C" void kernel_launch(void* const* d_in, const int* in_sizes, int n_in,
                              void* d_out, int out_size, void* d_ws, size_t ws_size,
                              hipStream_t stream) {
  const float* modal1 = (const float*)d_in[0];
  const float* modal2 = (const float*)d_in[1];
  const float* ln1_g  = (const float*)d_in[2];
  const float* ln1_b  = (const float*)d_in[3];
  const float* w_qkv1 = (const float*)d_in[4];
  const float* b_qkv1 = (const float*)d_in[5];
  const float* w_proj1= (const float*)d_in[6];
  const float* b_proj1= (const float*)d_in[7];
  const float* ln2_g  = (const float*)d_in[8];
  const float* ln2_b  = (const float*)d_in[9];
  const float* w_qkv2 = (const float*)d_in[10];
  const float* b_qkv2 = (const float*)d_in[11];
  const float* w_proj2= (const float*)d_in[12];
  const float* b_proj2= (const float*)d_in[13];
  float* out = (float*)d_out;

  const size_t BUFE = (size_t)NROW * EMB;       // 6291456 elems
  const size_t WQE  = (size_t)2 * 2304 * EMB;   // 3538944 elems
  const size_t WPE  = (size_t)2 * 768 * EMB;    // 1179648 elems
  u16* xn_hi = (u16*)d_ws;
  u16* xn_lo = xn_hi + BUFE;
  u16* q_hi  = xn_lo + BUFE;
  u16* q_lo  = q_hi + BUFE;
  u16* k_hi  = q_lo + BUFE;
  u16* k_lo  = k_hi + BUFE;
  u16* vT    = k_lo + BUFE;
  u16* wq_h  = vT + BUFE;
  u16* wq_l  = wq_h + WQE;
  u16* wp_sep= wq_l + WQE;                      // separate wp region (merged mode)
  u16* attn  = xn_hi;   // xn dead after k_qkv

  // merged mode needs 7*BUFE + 2*WQE + WPE u16 elems of workspace
  size_t need = (7 * BUFE + 2 * WQE + WPE) * sizeof(u16);
  bool merged = ws_size >= need;
  u16* wp_h = merged ? wp_sep : q_lo;           // fallback: alias dead q_lo (r11 scheme)

  int pre_grid = 4608 + NROW + (merged ? 1536 : 0);
  k_pre<<<pre_grid, 256, 0, stream>>>(w_qkv1, w_qkv2, wq_h, wq_l,
                                      modal1, modal2, ln1_g, ln1_b, ln2_g, ln2_b,
                                      xn_hi, xn_lo, w_proj1, w_proj2, wp_h);
  dim3 g2(32, 18, 2);
  k_qkv<<<g2, 256, 0, stream>>>(xn_hi, xn_lo, wq_h, wq_l, b_qkv1, b_qkv2,
                                q_hi, q_lo, k_hi, k_lo, vT);
  dim3 g3(16, 48);
  k_attn<<<g3, 256, 0, stream>>>(q_hi, q_lo, k_hi, k_lo, vT, attn);
  if (!merged) prep_wp<<<1536, 256, 0, stream>>>(w_proj1, w_proj2, wp_h);
  dim3 g4(64, 6, 2);
  k_proj<<<g4, 256, 0, stream>>>(attn, wp_h, modal1, modal2, b_proj1, b_proj2, out);
}